// Round 1
// baseline (214.404 us; speedup 1.0000x reference)
//
#include <hip/hip_runtime.h>

// Head: fused single-head causal attention. Round 5: 2-element persistent
// pipeline per wave. Grid = B/2 = 2048 one-wave blocks -> exactly 8
// blocks/CU, single residency round (no 2nd-round tail). Each wave
// processes batch elements 2b and 2b+1; the first two x-tiles of element
// 2b+1 are issued into the freed ta/tb register buffers BEFORE phase 2 of
// element 2b, so >=16 KB of HBM loads stay outstanding through the
// previously VMEM-dead softmax/PV phase. Weights register-resident
// (24 B-frags); softmax: no max-sub (|s|<~3), scale folded into Wq.
//
// mfma_f32_16x16x32_bf16 layouts (HW-verified, guide §3):
//   A-frag: A[m = lane&15][k = quad*8 + j]
//   B-frag: B[k = quad*8 + j][n = lane&15]
//   C/D   : col = lane&15, row = quad*4 + reg

#define TT 64
#define CC 128
#define HD 32

typedef __bf16 bf16_t;
typedef __bf16 bf8_t __attribute__((ext_vector_type(8)));
typedef __bf16 bf4_t __attribute__((ext_vector_type(4)));
typedef float  f4_t  __attribute__((ext_vector_type(4)));

// d_ws: wf[(n6*4 + kk)*64 + lane] = 16-byte bf8 B-frag.
// n6 = 0..5 (q lo/hi, k lo/hi, v lo/hi), kk = 0..3 (K blocks of 32).
// Element j = Wsel[(kk*32 + (lane>>4)*8 + j)][(n6&1)*16 + (lane&15)].
// Q-frags (n6<2) pre-scaled by 1/sqrt(32).
__global__ __launch_bounds__(256) void prep_weights(
    const float* __restrict__ Wq, const float* __restrict__ Wk,
    const float* __restrict__ Wv, bf16_t* __restrict__ wf)
{
  int t = blockIdx.x * 256 + threadIdx.x;   // 0..12287
  int j    = t & 7;
  int lane = (t >> 3) & 63;
  int kt   = (t >> 9) & 3;
  int n6   = t >> 11;
  int k    = kt * 32 + (lane >> 4) * 8 + j;
  int col  = (n6 & 1) * 16 + (lane & 15);
  const float* W = (n6 >> 1) == 0 ? Wq : ((n6 >> 1) == 1 ? Wk : Wv);
  float v = W[k * HD + col];
  if (n6 < 2) v *= 0.17677669529663687f;    // fold 1/sqrt(32) into Wq
  wf[t] = (bf16_t)v;
}

__global__ __launch_bounds__(64, 2) void head_fused(
    const float* __restrict__ x, const bf8_t* __restrict__ wf,
    float* __restrict__ out)
{
  __shared__ __align__(16) bf16_t qs[TT][40];   // q[row][d]        5120 B
  __shared__ __align__(16) bf16_t ks[TT][40];   // k[row][d]        5120 B
  __shared__ __align__(16) bf16_t vt[HD][72];   // v^T[d][row]      4608 B
  __shared__ __align__(16) bf16_t ps[16][72];   // P strip          2304 B
  // total 17152 B; 8 one-wave blocks/CU (VGPR-capped at 2 waves/EU)

  const int lane = threadIdx.x;      // 0..63, one wave
  const int quad = lane >> 4;
  const int l16  = lane & 15;
  const float* __restrict__ xb0 = x + (size_t)(2 * blockIdx.x) * (TT * CC);
  const float* __restrict__ xb1 = xb0 + TT * CC;
  float* __restrict__ ob0 = out + (size_t)(2 * blockIdx.x) * (TT * HD);
  float* __restrict__ ob1 = ob0 + TT * HD;

  const f4_t zero4 = {0.f, 0.f, 0.f, 0.f};

  bf8_t wfr[24];                     // register-resident weight B-frags (96 VGPR)
  float4 ta[8], tb[8];               // double-buffer x-tile staging (64 VGPR)

  // issue x-tile loads: 8x dwordx4 per tile (lane covers 32 B of row l16)
  auto load_tile = [&](float4* d, const float* __restrict__ xblk, int i) {
    #pragma unroll
    for (int kk = 0; kk < 4; ++kk) {
      const float* s = xblk + (16 * i + l16) * CC + kk * 32 + quad * 8;
      d[2 * kk]     = *(const float4*)s;
      d[2 * kk + 1] = *(const float4*)(s + 4);
    }
  };

  auto proj_tile = [&](const float4* d, int i) {
    f4_t acc[6];
    #pragma unroll
    for (int n = 0; n < 6; ++n) acc[n] = zero4;
    #pragma unroll
    for (int kk = 0; kk < 4; ++kk) {
      float4 f0 = d[2 * kk], f1 = d[2 * kk + 1];
      bf8_t a;
      a[0] = (bf16_t)f0.x; a[1] = (bf16_t)f0.y; a[2] = (bf16_t)f0.z; a[3] = (bf16_t)f0.w;
      a[4] = (bf16_t)f1.x; a[5] = (bf16_t)f1.y; a[6] = (bf16_t)f1.z; a[7] = (bf16_t)f1.w;
      #pragma unroll
      for (int n = 0; n < 6; ++n)
        acc[n] = __builtin_amdgcn_mfma_f32_16x16x32_bf16(a, wfr[n * 4 + kk], acc[n], 0, 0, 0);
    }
    #pragma unroll
    for (int r = 0; r < 4; ++r) {
      int row = 16 * i + quad * 4 + r;         // C/D: row = quad*4 + reg
      qs[row][l16]      = (bf16_t)acc[0][r];
      qs[row][16 + l16] = (bf16_t)acc[1][r];
      ks[row][l16]      = (bf16_t)acc[2][r];
      ks[row][16 + l16] = (bf16_t)acc[3][r];
    }
    bf4_t v0 = { (bf16_t)acc[4][0], (bf16_t)acc[4][1], (bf16_t)acc[4][2], (bf16_t)acc[4][3] };
    bf4_t v1 = { (bf16_t)acc[5][0], (bf16_t)acc[5][1], (bf16_t)acc[5][2], (bf16_t)acc[5][3] };
    *(bf4_t*)&vt[l16][16 * i + quad * 4]      = v0;   // tokens quad*4..+3 contiguous
    *(bf4_t*)&vt[16 + l16][16 * i + quad * 4] = v1;
  };

  // scores -> softmax -> PV per M-tile; reads qs/ks/vt written by proj_tile.
  // no barrier anywhere: single wave, DS ops in-order (compiler lgkmcnt waits)
  auto phase2 = [&](float* __restrict__ ob) {
    #pragma unroll
    for (int i = 0; i < 4; ++i) {
      f4_t sc[4];
      bf8_t aq = *(const bf8_t*)&qs[16 * i + l16][quad * 8];   // scale pre-folded
      #pragma unroll
      for (int j = 0; j < 4; ++j) {
        sc[j] = zero4;
        if (j <= i) {
          bf8_t bk = *(const bf8_t*)&ks[16 * j + l16][quad * 8];
          sc[j] = __builtin_amdgcn_mfma_f32_16x16x32_bf16(aq, bk, zero4, 0, 0, 0);
        }
      }
      #pragma unroll
      for (int r = 0; r < 4; ++r) {
        int rl = quad * 4 + r;
        float p[4];
        float psum = 0.f;
        #pragma unroll
        for (int j = 0; j < 4; ++j) {
          if (j <= i) {
            // no max-sub: |s| <= ~3 analytically, exp is safe
            bool valid = (j < i) | (l16 <= rl);  // diagonal-tile causal mask
            float e = __expf(sc[j][r]);
            p[j] = valid ? e : 0.f;
            psum += p[j];
          } else p[j] = 0.f;
        }
        #pragma unroll
        for (int off = 1; off < 16; off <<= 1)
          psum += __shfl_xor(psum, off);
        float inv = __builtin_amdgcn_rcpf(psum);   // psum >= diag term > 0
        #pragma unroll
        for (int j = 0; j < 4; ++j) {
          if (j <= i)             ps[rl][j * 16 + l16] = (bf16_t)(p[j] * inv);
          else if (j == (i | 1))  ps[rl][j * 16 + l16] = (bf16_t)0.f;  // zero-fill read range
        }
      }
      f4_t o0 = zero4, o1 = zero4;
      #pragma unroll
      for (int kk = 0; kk <= (i >> 1); ++kk) {     // skip all-zero K-tiles for i<2
        int k0 = kk * 32 + quad * 8;
        bf8_t ap  = *(const bf8_t*)&ps[l16][k0];
        bf8_t bv0 = *(const bf8_t*)&vt[l16][k0];
        bf8_t bv1 = *(const bf8_t*)&vt[16 + l16][k0];
        o0 = __builtin_amdgcn_mfma_f32_16x16x32_bf16(ap, bv0, o0, 0, 0, 0);
        o1 = __builtin_amdgcn_mfma_f32_16x16x32_bf16(ap, bv1, o1, 0, 0, 0);
      }
      #pragma unroll
      for (int r = 0; r < 4; ++r) {
        int row = 16 * i + quad * 4 + r;
        ob[row * HD + l16]      = o0[r];
        ob[row * HD + 16 + l16] = o1[r];
      }
    }
  };

  // ---------------- element 0: pipelined projection ----------------
  load_tile(ta, xb0, 0);             // issue tile 0 first
  #pragma unroll
  for (int t = 0; t < 24; ++t) wfr[t] = wf[t * 64 + lane];   // weights (L2-hot)
  load_tile(tb, xb0, 1);
  proj_tile(ta, 0);  load_tile(ta, xb0, 2);
  proj_tile(tb, 1);  load_tile(tb, xb0, 3);
  proj_tile(ta, 2);  load_tile(ta, xb1, 0);   // start element 1 prefetch NOW:
  proj_tile(tb, 3);  load_tile(tb, xb1, 1);   // 16 KB stays in flight through phase 2
  phase2(ob0);

  // ---------------- element 1 ----------------
  proj_tile(ta, 0);  load_tile(ta, xb1, 2);
  proj_tile(tb, 1);  load_tile(tb, xb1, 3);
  proj_tile(ta, 2);
  proj_tile(tb, 3);
  phase2(ob1);
}

extern "C" void kernel_launch(void* const* d_in, const int* in_sizes, int n_in,
                              void* d_out, int out_size, void* d_ws, size_t ws_size,
                              hipStream_t stream) {
  const float* x  = (const float*)d_in[0];
  const float* Wq = (const float*)d_in[1];
  const float* Wk = (const float*)d_in[2];
  const float* Wv = (const float*)d_in[3];
  float* out = (float*)d_out;
  bf16_t* wf = (bf16_t*)d_ws;                  // 12288 bf16 = 24 KB
  int B = in_sizes[0] / (TT * CC);             // 4096

  prep_weights<<<dim3(48), dim3(256), 0, stream>>>(Wq, Wk, Wv, wf);
  head_fused<<<dim3(B / 2), dim3(64), 0, stream>>>(x, (const bf8_t*)wf, out);
}

// Round 2
// 206.342 us; speedup vs baseline: 1.0391x; 1.0391x over previous
//
#include <hip/hip_runtime.h>

// Head: fused single-head causal attention. Round 6: MFMA row-sum softmax.
// One wave per batch element (64-thr blocks, grid=4096), zero barriers.
// Weights register-resident (24 B-frags); x software-pipelined register
// double-buffer. Softmax: no max-sub (|s|<~3), scale folded into Wq.
// NEW: denominator via ones-column MFMA (osum = mfma(ap, ones)) instead of
// 4-step shfl_xor chains; P stored unnormalized, O divided by row-sum at
// the end. proj(tile3) deferred past sm_tile(0,1) so its 8 KB of loads
// ride through half of phase 2 (only +32 VGPR live, unlike round 5).
//
// mfma_f32_16x16x32_bf16 layouts (HW-verified, guide §3):
//   A-frag: A[m = lane&15][k = quad*8 + j]
//   B-frag: B[k = quad*8 + j][n = lane&15]
//   C/D   : col = lane&15, row = quad*4 + reg

#define TT 64
#define CC 128
#define HD 32

typedef __bf16 bf16_t;
typedef __bf16 bf8_t __attribute__((ext_vector_type(8)));
typedef __bf16 bf4_t __attribute__((ext_vector_type(4)));
typedef float  f4_t  __attribute__((ext_vector_type(4)));

// d_ws: wf[(n6*4 + kk)*64 + lane] = 16-byte bf8 B-frag.
// n6 = 0..5 (q lo/hi, k lo/hi, v lo/hi), kk = 0..3 (K blocks of 32).
// Element j = Wsel[(kk*32 + (lane>>4)*8 + j)][(n6&1)*16 + (lane&15)].
// Q-frags (n6<2) pre-scaled by 1/sqrt(32).
__global__ __launch_bounds__(256) void prep_weights(
    const float* __restrict__ Wq, const float* __restrict__ Wk,
    const float* __restrict__ Wv, bf16_t* __restrict__ wf)
{
  int t = blockIdx.x * 256 + threadIdx.x;   // 0..12287
  int j    = t & 7;
  int lane = (t >> 3) & 63;
  int kt   = (t >> 9) & 3;
  int n6   = t >> 11;
  int k    = kt * 32 + (lane >> 4) * 8 + j;
  int col  = (n6 & 1) * 16 + (lane & 15);
  const float* W = (n6 >> 1) == 0 ? Wq : ((n6 >> 1) == 1 ? Wk : Wv);
  float v = W[k * HD + col];
  if (n6 < 2) v *= 0.17677669529663687f;    // fold 1/sqrt(32) into Wq
  wf[t] = (bf16_t)v;
}

__global__ __launch_bounds__(64, 2) void head_fused(
    const float* __restrict__ x, const bf8_t* __restrict__ wf,
    float* __restrict__ out)
{
  __shared__ __align__(16) bf16_t qs[TT][40];   // q[row][d]        5120 B
  __shared__ __align__(16) bf16_t ks[TT][40];   // k[row][d]        5120 B
  __shared__ __align__(16) bf16_t vt[HD][72];   // v^T[d][row]      4608 B
  __shared__ __align__(16) bf16_t ps[16][72];   // P strip (unnorm) 2304 B
  // total 17152 B; 8 one-wave blocks/CU (VGPR-capped at 2 waves/EU)

  const int lane = threadIdx.x;      // 0..63, one wave
  const int quad = lane >> 4;
  const int l16  = lane & 15;
  const int b    = blockIdx.x;
  const float* __restrict__ xblk = x + (size_t)b * (TT * CC);
  float* __restrict__ ob = out + (size_t)b * (TT * HD);

  const f4_t zero4 = {0.f, 0.f, 0.f, 0.f};
  bf8_t ones8;
  #pragma unroll
  for (int t = 0; t < 8; ++t) ones8[t] = (bf16_t)1.0f;

  bf8_t wfr[24];                     // register-resident weight B-frags (96 VGPR)
  float4 ta[8], tb[8];               // double-buffer x-tile staging (64 VGPR)

  // issue x-tile loads: 8x dwordx4 per tile (lane covers 32 B of row l16)
  auto load_tile = [&](float4* d, int i) {
    #pragma unroll
    for (int kk = 0; kk < 4; ++kk) {
      const float* s = xblk + (16 * i + l16) * CC + kk * 32 + quad * 8;
      d[2 * kk]     = *(const float4*)s;
      d[2 * kk + 1] = *(const float4*)(s + 4);
    }
  };

  auto proj_tile = [&](const float4* d, int i) {
    f4_t acc[6];
    #pragma unroll
    for (int n = 0; n < 6; ++n) acc[n] = zero4;
    #pragma unroll
    for (int kk = 0; kk < 4; ++kk) {
      float4 f0 = d[2 * kk], f1 = d[2 * kk + 1];
      bf8_t a;
      a[0] = (bf16_t)f0.x; a[1] = (bf16_t)f0.y; a[2] = (bf16_t)f0.z; a[3] = (bf16_t)f0.w;
      a[4] = (bf16_t)f1.x; a[5] = (bf16_t)f1.y; a[6] = (bf16_t)f1.z; a[7] = (bf16_t)f1.w;
      #pragma unroll
      for (int n = 0; n < 6; ++n)
        acc[n] = __builtin_amdgcn_mfma_f32_16x16x32_bf16(a, wfr[n * 4 + kk], acc[n], 0, 0, 0);
    }
    #pragma unroll
    for (int r = 0; r < 4; ++r) {
      int row = 16 * i + quad * 4 + r;         // C/D: row = quad*4 + reg
      qs[row][l16]      = (bf16_t)acc[0][r];
      qs[row][16 + l16] = (bf16_t)acc[1][r];
      ks[row][l16]      = (bf16_t)acc[2][r];
      ks[row][16 + l16] = (bf16_t)acc[3][r];
    }
    bf4_t v0 = { (bf16_t)acc[4][0], (bf16_t)acc[4][1], (bf16_t)acc[4][2], (bf16_t)acc[4][3] };
    bf4_t v1 = { (bf16_t)acc[5][0], (bf16_t)acc[5][1], (bf16_t)acc[5][2], (bf16_t)acc[5][3] };
    *(bf4_t*)&vt[l16][16 * i + quad * 4]      = v0;   // tokens quad*4..+3 contiguous
    *(bf4_t*)&vt[16 + l16][16 * i + quad * 4] = v1;
  };

  // scores -> exp (unnormalized, bf16) -> PV + ones-MFMA row-sum -> divide.
  // no barrier anywhere: single wave, DS ops in-order (compiler lgkmcnt waits)
  auto sm_tile = [&](int i) {
    f4_t sc[4];
    bf8_t aq = *(const bf8_t*)&qs[16 * i + l16][quad * 8];   // scale pre-folded
    #pragma unroll
    for (int j = 0; j < 4; ++j) {
      sc[j] = zero4;
      if (j <= i) {
        bf8_t bk = *(const bf8_t*)&ks[16 * j + l16][quad * 8];
        sc[j] = __builtin_amdgcn_mfma_f32_16x16x32_bf16(aq, bk, zero4, 0, 0, 0);
      }
    }
    #pragma unroll
    for (int r = 0; r < 4; ++r) {
      int rl = quad * 4 + r;
      #pragma unroll
      for (int j = 0; j < 4; ++j) {
        if (j <= i) {
          // no max-sub: |s| <= ~3 analytically, exp is safe; store raw exp
          bool valid = (j < i) | (l16 <= rl);  // diagonal-tile causal mask
          float e = __expf(sc[j][r]);
          ps[rl][j * 16 + l16] = (bf16_t)(valid ? e : 0.f);
        } else if (j == (i | 1)) {
          ps[rl][j * 16 + l16] = (bf16_t)0.f;  // zero-fill read range
        }
      }
    }
    f4_t o0 = zero4, o1 = zero4, osum = zero4;
    #pragma unroll
    for (int kk = 0; kk <= (i >> 1); ++kk) {     // skip all-zero K-tiles for i<2
      int k0 = kk * 32 + quad * 8;
      bf8_t ap  = *(const bf8_t*)&ps[l16][k0];
      bf8_t bv0 = *(const bf8_t*)&vt[l16][k0];
      bf8_t bv1 = *(const bf8_t*)&vt[16 + l16][k0];
      o0   = __builtin_amdgcn_mfma_f32_16x16x32_bf16(ap, bv0, o0, 0, 0, 0);
      o1   = __builtin_amdgcn_mfma_f32_16x16x32_bf16(ap, bv1, o1, 0, 0, 0);
      // D[m][n] = rowsum[m] for every n: each lane gets its row's denominator
      osum = __builtin_amdgcn_mfma_f32_16x16x32_bf16(ap, ones8, osum, 0, 0, 0);
    }
    #pragma unroll
    for (int r = 0; r < 4; ++r) {
      int row = 16 * i + quad * 4 + r;
      float inv = __builtin_amdgcn_rcpf(osum[r]);   // >= exp(diag) > 0
      ob[row * HD + l16]      = o0[r] * inv;
      ob[row * HD + 16 + l16] = o1[r] * inv;
    }
  };

  // ---------------- phase 1: pipelined projection ----------------
  load_tile(ta, 0);                  // issue tile 0 first
  #pragma unroll
  for (int t = 0; t < 24; ++t) wfr[t] = wf[t * 64 + lane];   // weights (L2-hot)
  load_tile(tb, 1);
  proj_tile(ta, 0);  load_tile(ta, 2);
  proj_tile(tb, 1);  load_tile(tb, 3);
  proj_tile(ta, 2);
  // ---------------- phase 2 interleaved with deferred proj(3) ----------------
  sm_tile(0);                        // tile3 (tb) loads still in flight here
  sm_tile(1);
  proj_tile(tb, 3);
  sm_tile(2);
  sm_tile(3);
}

extern "C" void kernel_launch(void* const* d_in, const int* in_sizes, int n_in,
                              void* d_out, int out_size, void* d_ws, size_t ws_size,
                              hipStream_t stream) {
  const float* x  = (const float*)d_in[0];
  const float* Wq = (const float*)d_in[1];
  const float* Wk = (const float*)d_in[2];
  const float* Wv = (const float*)d_in[3];
  float* out = (float*)d_out;
  bf16_t* wf = (bf16_t*)d_ws;                  // 12288 bf16 = 24 KB
  int B = in_sizes[0] / (TT * CC);             // 4096

  prep_weights<<<dim3(48), dim3(256), 0, stream>>>(Wq, Wk, Wv, wf);
  head_fused<<<dim3(B), dim3(64), 0, stream>>>(x, (const bf8_t*)wf, out);
}